// Round 15
// baseline (341.111 us; speedup 1.0000x reference)
//
#include <hip/hip_runtime.h>

typedef __attribute__((ext_vector_type(8))) short short8;
typedef __attribute__((ext_vector_type(4))) float f32x4;
typedef unsigned short u16;
typedef unsigned int u32;

__device__ __forceinline__ u16 f2bf(float f) {
  u32 u = __float_as_uint(f);
  u = (u + 0x7fffu + ((u >> 16) & 1u)) >> 16;
  return (u16)u;
}
__device__ __forceinline__ float bf2f(u16 v) { return __uint_as_float((u32)v << 16); }
__device__ __forceinline__ void atomAddF(float* p, float v) { unsafeAtomicAdd(p, v); }
__device__ __forceinline__ void addp(float* v, u32 p) {
  v[0] += bf2f((u16)p);
  v[1] += bf2f((u16)(p >> 16));
}

// ---- prep: pack bf16 weights + x->bf16 + graph bounds + deg count/ord ---- grid E/256
// deg/gcnt/bns zeroed by hipMemsetAsync beforehand.
__global__ void prep_k(const float* __restrict__ Wm1, const float* __restrict__ We1,
                       const float* __restrict__ Ws1, const float* __restrict__ Wm2,
                       const float* __restrict__ Wl1, const float* __restrict__ x,
                       const int* __restrict__ batch, const int* __restrict__ ei,
                       u16* __restrict__ Wp1, u16* __restrict__ Wp2, u16* __restrict__ Wp3,
                       u16* __restrict__ xbf, int* __restrict__ gstart,
                       int* __restrict__ gend, int* __restrict__ deg,
                       int* __restrict__ ord, int N, int E) {
  int tid = blockIdx.x * 256 + threadIdx.x;
  if (tid < 64 * 192) {  // Wcat1 = [Wm1(16); We1(4); Ws1(16)], pad K to 64
    int k = tid / 192, n = tid % 192;
    float v = 0.f;
    if (k < 16) v = Wm1[k * 192 + n];
    else if (k < 20) v = We1[(k - 16) * 192 + n];
    else if (k < 36) v = Ws1[(k - 20) * 192 + n];
    Wp1[((k >> 3) * 192 + n) * 8 + (k & 7)] = f2bf(v);
  }
  if (tid < 224 * 208) {  // W_msg2, pad K 208->224
    int k = tid / 208, n = tid % 208;
    float v = (k < 208) ? Wm2[k * 208 + n] : 0.f;
    Wp2[((k >> 3) * 208 + n) * 8 + (k & 7)] = f2bf(v);
  }
  if (tid < N * 8) {  // x -> bf16, 2 elems/thread
    float2 p = *(const float2*)(x + (size_t)tid * 2);
    *(u32*)(xbf + (size_t)tid * 2) = (u32)f2bf(p.x) | ((u32)f2bf(p.y) << 16);
  }
  if (tid < N) {
    int b = batch[tid];
    if (tid == 0 || batch[tid - 1] != b) gstart[b] = tid;
    if (tid == N - 1 || batch[tid + 1] != b) gend[b] = tid;
  }
  if (tid < 1248 * 624) {
    int k = tid / 624, n = tid % 624;
    Wp3[((size_t)(k >> 3) * 624 + n) * 8 + (k & 7)] = f2bf(Wl1[(size_t)k * 624 + n]);
  }
  if (tid < E) ord[tid] = atomicAdd(&deg[ei[E + tid]], 1);  // count + ordinal
}

__global__ void scanA_k(const int* __restrict__ deg, int* __restrict__ bsum, int N) {
  __shared__ int sh[256];
  int t = threadIdx.x;
  int i = blockIdx.x * 256 + t;
  sh[t] = (i < N) ? deg[i] : 0;
  __syncthreads();
  for (int off = 128; off > 0; off >>= 1) {
    if (t < off) sh[t] += sh[t + off];
    __syncthreads();
  }
  if (t == 0) bsum[blockIdx.x] = sh[0];
}

__global__ void scanC_k(const int* __restrict__ deg, const int* __restrict__ bsum,
                        int* __restrict__ rowptr, int N, int nb) {
  __shared__ int sb2[256];
  __shared__ int sh[256];
  int t = threadIdx.x;
  int bv = (t < nb) ? bsum[t] : 0;
  sb2[t] = bv;
  __syncthreads();
  for (int off = 1; off < 256; off <<= 1) {
    int u = (t >= off) ? sb2[t - off] : 0;
    __syncthreads();
    sb2[t] += u;
    __syncthreads();
  }
  int bpref = (blockIdx.x == 0) ? 0 : sb2[blockIdx.x - 1];
  int i = blockIdx.x * 256 + t;
  int d = (i < N) ? deg[i] : 0;
  sh[t] = d;
  __syncthreads();
  for (int off = 1; off < 256; off <<= 1) {
    int u = (t >= off) ? sh[t - off] : 0;
    __syncthreads();
    sh[t] += u;
    __syncthreads();
  }
  int excl = sh[t] - d + bpref;
  if (i < N) {
    rowptr[i] = excl;
    if (i == N - 1) rowptr[N] = excl + d;
  }
}

// ---- pass 1: bucket by slot>>15, dense appends (slots are dense in [0,E)) ----
__global__ void bucket_k(const int* __restrict__ ei, const float* __restrict__ ea,
                         const int* __restrict__ ord, const int* __restrict__ rowptr,
                         int* __restrict__ gcnt, int4* __restrict__ bkt, int E) {
  __shared__ int hcnt[32];
  __shared__ int hbase[32];
  int tid = threadIdx.x;
  int e = blockIdx.x * 256 + tid;
  if (tid < 32) hcnt[tid] = 0;
  __syncthreads();
  bool valid = e < E;
  int slot = 0, b = 0, myofs = 0, s = 0;
  u32 p0 = 0, p1 = 0;
  if (valid) {
    s = ei[e];
    int d = ei[E + e];
    float4 w = *(const float4*)(ea + (size_t)e * 4);
    p0 = (u32)f2bf(w.x) | ((u32)f2bf(w.y) << 16);
    p1 = (u32)f2bf(w.z) | ((u32)f2bf(w.w) << 16);
    slot = rowptr[d] + ord[e];
    b = slot >> 15;
    myofs = atomicAdd(&hcnt[b], 1);
  }
  __syncthreads();
  if (tid < 32) hbase[tid] = hcnt[tid] ? atomicAdd(&gcnt[tid], hcnt[tid]) : 0;
  __syncthreads();
  if (valid) {
    int pos = (b << 15) + hbase[b] + myofs;
    bkt[pos] = make_int4(slot, s, (int)p0, (int)p1);
  }
}

// ---- pass 2: dense read, L2-confined ordered write ----
__global__ void order_k(const int4* __restrict__ bkt, int4* __restrict__ se16, int E) {
  int p = blockIdx.x * 256 + threadIdx.x;
  if (p >= E) return;
  int4 ent = bkt[p];
  se16[ent.x] = make_int4(ent.y, ent.z, ent.w, 0);
}

// ---- CONV1: gather1 (16 lanes/node) + U1(LDS) + gemm1 MFMA + h1bf + bn1 stats ----
// grid ceil(N/16), block 256 (4 waves)
__global__ void __launch_bounds__(256) conv1_k(
    const int4* __restrict__ se16, const int* __restrict__ rowptr,
    const u16* __restrict__ xbf, const u16* __restrict__ Bp,
    const float* __restrict__ bm1, const float* __restrict__ be1,
    const float* __restrict__ bs1, u16* __restrict__ acc1c, u16* __restrict__ h1bf,
    float* __restrict__ bns1p, int N) {
  __shared__ __align__(16) u16 Uls[16][72];
  __shared__ float degls[16];
  int tid = threadIdx.x;
  int nl = tid >> 4, q = tid & 15;
  int n = blockIdx.x * 16 + nl;
  bool nval = n < N;
  int j0 = nval ? rowptr[n] : 0;
  int j1 = nval ? rowptr[n + 1] : 0;
  float v[20];
#pragma unroll
  for (int i = 0; i < 20; ++i) v[i] = 0.f;
  for (int j = j0 + q; j < j1; j += 16) {
    int4 p = se16[j];
    const uint4* xs = (const uint4*)(xbf + (size_t)p.x * 16);
    uint4 x0 = xs[0], x1 = xs[1];
    addp(v + 0, x0.x); addp(v + 2, x0.y); addp(v + 4, x0.z); addp(v + 6, x0.w);
    addp(v + 8, x1.x); addp(v + 10, x1.y); addp(v + 12, x1.z); addp(v + 14, x1.w);
    addp(v + 16, (u32)p.y); addp(v + 18, (u32)p.z);
  }
#pragma unroll
  for (int i = 0; i < 20; ++i) {
    v[i] += __shfl_xor(v[i], 1);
    v[i] += __shfl_xor(v[i], 2);
    v[i] += __shfl_xor(v[i], 4);
    v[i] += __shfl_xor(v[i], 8);
  }
  float degf = (float)(j1 - j0);
  const u16* xr = xbf + (size_t)n * 16;
  {  // U1 row -> LDS: [sums20, x(n)16, 0..]; lane q writes elems q*4..q*4+3
    u32 w2[2];
#pragma unroll
    for (int jj = 0; jj < 2; ++jj) {
      int t0 = q * 4 + 2 * jj, t1 = t0 + 1;
      u16 b0 = (t0 < 20) ? f2bf(v[t0]) : ((t0 < 36 && nval) ? xr[t0 - 20] : (u16)0);
      u16 b1 = (t1 < 20) ? f2bf(v[t1]) : ((t1 < 36 && nval) ? xr[t1 - 20] : (u16)0);
      w2[jj] = (u32)b0 | ((u32)b1 << 16);
    }
    *(uint2*)&Uls[nl][q * 4] = make_uint2(w2[0], w2[1]);
  }
  if (nval) {  // acc1c row: [sx16, sea4, deg, 0..]; lane q -> elems 2q,2q+1
    int t0 = q * 2, t1 = t0 + 1;
    float f0 = (t0 < 20) ? v[t0] : ((t0 == 20) ? degf : 0.f);
    float f1 = (t1 < 20) ? v[t1] : ((t1 == 20) ? degf : 0.f);
    *(u32*)(acc1c + (size_t)n * 32 + q * 2) = (u32)f2bf(f0) | ((u32)f2bf(f1) << 16);
  }
  if (q == 0) degls[nl] = degf;
  __syncthreads();
  // Phase B: 12 n-tile jobs over 4 waves
  int w = tid >> 6, lane = tid & 63, rc = lane & 15, qd = lane >> 4;
  int slice = (blockIdx.x & 63) * 384;
  for (int nt = w; nt < 12; nt += 4) {
    f32x4 acc = {0.f, 0.f, 0.f, 0.f};
#pragma unroll
    for (int kb = 0; kb < 2; ++kb) {
      short8 av = *(const short8*)&Uls[rc][kb * 32 + qd * 8];
      short8 bv = *(const short8*)(Bp + (size_t)((kb * 4 + qd) * 192 + nt * 16 + rc) * 8);
      acc = __builtin_amdgcn_mfma_f32_16x16x32_bf16(av, bv, acc, 0, 0, 0);
    }
    int col = nt * 16 + rc;
    float bb = bm1[col] + be1[col], bsv = bs1[col];
    float ps = 0.f, pq = 0.f;
#pragma unroll
    for (int r = 0; r < 4; ++r) {
      int ml = qd * 4 + r;
      int m = blockIdx.x * 16 + ml;
      float val = acc[r] + degls[ml] * bb + bsv;
      if (m < N) {
        h1bf[(size_t)m * 192 + col] = f2bf(val);
        ps += val;
        pq += val * val;
      }
    }
    ps += __shfl_xor(ps, 16); ps += __shfl_xor(ps, 32);
    pq += __shfl_xor(pq, 16); pq += __shfl_xor(pq, 32);
    if (qd == 0) {
      atomAddF(&bns1p[slice + col], ps);
      atomAddF(&bns1p[slice + 192 + col], pq);
    }
  }
}

// ---- bn1 finalize ---- 1 block, 256 threads
__global__ void bnfin1_k(const float* __restrict__ bns1p, const float* __restrict__ g1,
                         const float* __restrict__ bta1, float Ninv,
                         float* __restrict__ aff1) {
  int c = threadIdx.x;
  if (c >= 192) return;
  float sm = 0.f, sq = 0.f;
  for (int k = 0; k < 64; ++k) {
    sm += bns1p[k * 384 + c];
    sq += bns1p[k * 384 + 192 + c];
  }
  float m1 = sm * Ninv;
  float var = sq * Ninv - m1 * m1;
  float s1 = g1[c] * rsqrtf(var + 1e-5f);
  aff1[c] = s1;
  aff1[192 + c] = bta1[c] - m1 * s1;
}

// ---- CONV2: gather2 (16 lanes/node) + U2(LDS) + gemmq2 (V in LDS) + gemm2 + bn2 ----
// grid ceil(N/16), block 256 (4 waves)
__global__ void __launch_bounds__(256) conv2_k(
    const int4* __restrict__ se16, const int* __restrict__ rowptr,
    const u16* __restrict__ acc1c, const u16* __restrict__ h1bf,
    const u16* __restrict__ xbf, const u16* __restrict__ Bp1, const u16* __restrict__ Bp2,
    const float* __restrict__ bm1, const float* __restrict__ be1,
    const float* __restrict__ bs1, const float* __restrict__ aff1,
    const float* __restrict__ We2, const float* __restrict__ bm2,
    const float* __restrict__ be2, float* __restrict__ bns2p,
    u16* __restrict__ h2bf, int N) {
  __shared__ __align__(16) u16 Uls[16][72];
  __shared__ __align__(16) u16 Vls[16][232];
  __shared__ float degls[16], sdegls[16], eals[16][4];
  int tid = threadIdx.x;
  int nl = tid >> 4, q = tid & 15;
  int n = blockIdx.x * 16 + nl;
  bool nval = n < N;
  int j0 = nval ? rowptr[n] : 0;
  int j1 = nval ? rowptr[n + 1] : 0;
  float v[21];
#pragma unroll
  for (int i = 0; i < 21; ++i) v[i] = 0.f;
  for (int j = j0 + q; j < j1; j += 16) {
    int s = se16[j].x;
    const uint4* cr = (const uint4*)(acc1c + (size_t)s * 32);
    uint4 c0 = cr[0], c1 = cr[1], c2 = cr[2];
    addp(v + 0, c0.x); addp(v + 2, c0.y); addp(v + 4, c0.z); addp(v + 6, c0.w);
    addp(v + 8, c1.x); addp(v + 10, c1.y); addp(v + 12, c1.z); addp(v + 14, c1.w);
    addp(v + 16, c2.x); addp(v + 18, c2.y);
    v[20] += bf2f((u16)c2.z);
  }
#pragma unroll
  for (int i = 0; i < 21; ++i) {
    v[i] += __shfl_xor(v[i], 1);
    v[i] += __shfl_xor(v[i], 2);
    v[i] += __shfl_xor(v[i], 4);
    v[i] += __shfl_xor(v[i], 8);
  }
  const u16* selfr = acc1c + (size_t)n * 32;
  {  // U2 row -> LDS: [sums20, self sx16, 0..]; lane q writes elems q*4..q*4+3
    u32 w2[2];
#pragma unroll
    for (int jj = 0; jj < 2; ++jj) {
      int t0 = q * 4 + 2 * jj, t1 = t0 + 1;
      u16 b0 = (t0 < 20) ? f2bf(v[t0]) : ((t0 < 36 && nval) ? selfr[t0 - 20] : (u16)0);
      u16 b1 = (t1 < 20) ? f2bf(v[t1]) : ((t1 < 36 && nval) ? selfr[t1 - 20] : (u16)0);
      w2[jj] = (u32)b0 | ((u32)b1 << 16);
    }
    *(uint2*)&Uls[nl][q * 4] = make_uint2(w2[0], w2[1]);
  }
  {  // V tail cols [192..224): self sx16 then zeros; lane q -> elems 192+2q, +1
    int t0 = q * 2, t1 = t0 + 1;
    u16 b0 = (t0 < 16 && nval) ? selfr[t0] : (u16)0;
    u16 b1 = (t1 < 16 && nval) ? selfr[t1] : (u16)0;
    *(u32*)&Vls[nl][192 + q * 2] = (u32)b0 | ((u32)b1 << 16);
  }
  if (q == 0) sdegls[nl] = v[20];
  if (q == 1) degls[nl] = nval ? bf2f(selfr[20]) : 0.f;
  if (q == 2) {
#pragma unroll
    for (int k = 0; k < 4; ++k) eals[nl][k] = nval ? bf2f(selfr[16 + k]) : 0.f;
  }
  __syncthreads();
  // Phase B: gemmq2 -> Vls[:,0..192), 12 jobs / 4 waves
  int w = tid >> 6, lane = tid & 63, rc = lane & 15, qd = lane >> 4;
  for (int nt = w; nt < 12; nt += 4) {
    f32x4 acc = {0.f, 0.f, 0.f, 0.f};
#pragma unroll
    for (int kb = 0; kb < 2; ++kb) {
      short8 av = *(const short8*)&Uls[rc][kb * 32 + qd * 8];
      short8 bv = *(const short8*)(Bp1 + (size_t)((kb * 4 + qd) * 192 + nt * 16 + rc) * 8);
      acc = __builtin_amdgcn_mfma_f32_16x16x32_bf16(av, bv, acc, 0, 0, 0);
    }
    int col = nt * 16 + rc;
    float s1 = aff1[col], t1 = aff1[192 + col];
    float bb = bm1[col] + be1[col], bsv = bs1[col];
#pragma unroll
    for (int r = 0; r < 4; ++r) {
      int ml = qd * 4 + r;
      float qv = acc[r] + sdegls[ml] * bb + degls[ml] * bsv;
      Vls[ml][col] = f2bf(qv * s1 + degls[ml] * t1);
    }
  }
  __syncthreads();
  // Phase C: gemm2, A = Vls, 13 jobs / 4 waves
  int slice = (blockIdx.x & 63) * 832;
  for (int nt = w; nt < 13; nt += 4) {
    f32x4 acc = {0.f, 0.f, 0.f, 0.f};
#pragma unroll
    for (int kb = 0; kb < 7; ++kb) {
      short8 av = *(const short8*)&Vls[rc][kb * 32 + qd * 8];
      short8 bv = *(const short8*)(Bp2 + (size_t)((kb * 4 + qd) * 208 + nt * 16 + rc) * 8);
      acc = __builtin_amdgcn_mfma_f32_16x16x32_bf16(av, bv, acc, 0, 0, 0);
    }
    int col = nt * 16 + rc;
    float w0 = We2[col], w1 = We2[208 + col], w2 = We2[416 + col], w3 = We2[624 + col];
    float bb2 = bm2[col] + be2[col];
    bool c192 = col < 192;
    float s1 = c192 ? aff1[col] : 0.f;
    float t1 = c192 ? aff1[192 + col] : 0.f;
    float ps = 0.f, pq = 0.f;
#pragma unroll
    for (int r = 0; r < 4; ++r) {
      int ml = qd * 4 + r;
      int m = blockIdx.x * 16 + ml;
      bool mv = m < N;
      float x1 = 0.f;
      if (mv) {
        x1 = c192 ? (bf2f(h1bf[(size_t)m * 192 + col]) * s1 + t1)
                  : bf2f(xbf[(size_t)m * 16 + (col - 192)]);
      }
      float val = acc[r] + eals[ml][0] * w0 + eals[ml][1] * w1 + eals[ml][2] * w2 +
                  eals[ml][3] * w3 + degls[ml] * bb2 + x1;
      if (mv) {
        h2bf[(size_t)m * 208 + col] = f2bf(val);
        ps += val;
        pq += val * val;
      }
    }
    ps += __shfl_xor(ps, 16); ps += __shfl_xor(ps, 32);
    pq += __shfl_xor(pq, 16); pq += __shfl_xor(pq, 32);
    if (qd == 0) {
      atomAddF(&bns2p[slice + col], ps);
      atomAddF(&bns2p[slice + 416 + col], pq);
    }
  }
}

// ---- bn finalize: unified affine table ---- grid 2x256
__global__ void bnfin2_k(const float* __restrict__ bns2p, const float* __restrict__ aff1,
                         const float* __restrict__ g2, const float* __restrict__ bta2,
                         float Ninv, float* __restrict__ aff) {
  int f = blockIdx.x * 256 + threadIdx.x;
  if (f >= 416) return;
  float sc, sh;
  if (f < 208) {
    float sm = 0.f, sq = 0.f;
    for (int k = 0; k < 64; ++k) {
      sm += bns2p[k * 832 + f];
      sq += bns2p[k * 832 + 416 + f];
    }
    float m2 = sm * Ninv;
    float var = sq * Ninv - m2 * m2;
    sc = g2[f] * rsqrtf(var + 1e-5f);
    sh = bta2[f] - m2 * sc;
  } else if (f < 400) {
    sc = aff1[f - 208];
    sh = aff1[192 + (f - 208)];
  } else {
    sc = 1.f;
    sh = 0.f;
  }
  aff[f] = sc;
  aff[416 + f] = sh;
}

// ---- pooling: feature-pair threads, partial stores ---- grid=(64,16), block=256
__global__ void pool_k(const u16* __restrict__ h2bf, const u16* __restrict__ h1bf,
                       const u16* __restrict__ xbf, const float* __restrict__ aff,
                       const int* __restrict__ gstart, const int* __restrict__ gend,
                       float* __restrict__ psp, float* __restrict__ pmp) {
  int b = blockIdx.x, sub = blockIdx.y;
  int t = threadIdx.x;
  if (t >= 208) return;
  int s0 = gstart[b], e0 = gend[b];
  int cnt = (s0 <= e0) ? e0 - s0 + 1 : 0;
  int per = (cnt + 15) >> 4;
  int n0 = s0 + sub * per;
  int n1 = min(n0 + per, s0 + cnt);
  int f = 2 * t;
  const u16* src;
  int stride;
  if (f < 208) { src = h2bf + f; stride = 208; }
  else if (f < 400) { src = h1bf + (f - 208); stride = 192; }
  else { src = xbf + (f - 400); stride = 16; }
  float sc0 = aff[f], sc1 = aff[f + 1];
  float sh0 = aff[416 + f], sh1 = aff[417 + f];
  float s0f = 0.f, s1f = 0.f, m0f = -3.4e38f, m1f = -3.4e38f;
  for (int n = n0; n < n1; ++n) {
    u32 p = *(const u32*)(src + (size_t)n * stride);
    float v0 = bf2f((u16)p) * sc0 + sh0;
    float v1 = bf2f((u16)(p >> 16)) * sc1 + sh1;
    s0f += v0; s1f += v1;
    m0f = fmaxf(m0f, v0); m1f = fmaxf(m1f, v1);
  }
  size_t idx = ((size_t)(b * 16 + sub)) * 416 + f;
  *(float2*)(psp + idx) = make_float2(s0f, s1f);
  *(float2*)(pmp + idx) = make_float2(m0f, m1f);
}

// ---- pooled partial reduce -> bf16 A matrix [64 x 1248] ---- grid=64, block=256
__global__ void pooledprep_k(const float* __restrict__ psp, const float* __restrict__ pmp,
                             const int* __restrict__ gstart, const int* __restrict__ gend,
                             u16* __restrict__ Apool) {
  int b = blockIdx.x, t = threadIdx.x;
  int cnt = gend[b] - gstart[b] + 1;
  float inv = 1.f / (float)max(cnt, 1);
  for (int f = t; f < 416; f += 256) {
    float s = 0.f, m = -3.4e38f;
    for (int k = 0; k < 16; ++k) {
      size_t idx = ((size_t)(b * 16 + k)) * 416 + f;
      s += psp[idx];
      m = fmaxf(m, pmp[idx]);
    }
    u16* row = Apool + (size_t)b * 1248;
    row[f] = f2bf(s);
    row[416 + f] = f2bf((cnt > 0) ? m : 0.f);
    row[832 + f] = f2bf(s * inv);
  }
}

// ---- MLP layer 1 via MFMA ---- grid=(4,39), block=64
__global__ void mlpgemm_k(const u16* __restrict__ A, const u16* __restrict__ Bp,
                          const float* __restrict__ b1, const float* __restrict__ al,
                          float* __restrict__ hid) {
  int lane = threadIdx.x;
  int mt = blockIdx.x, nt = blockIdx.y;
  int rc = lane & 15, qd = lane >> 4;
  f32x4 acc = {0.f, 0.f, 0.f, 0.f};
  const u16* Ap = A + (size_t)(mt * 16 + rc) * 1248 + qd * 8;
  const u16* Bq = Bp + (size_t)(qd * 624 + nt * 16 + rc) * 8;
  for (int kb = 0; kb < 39; ++kb) {
    short8 av = *(const short8*)(Ap + kb * 32);
    short8 bv = *(const short8*)(Bq + (size_t)kb * 4 * 624 * 8);
    acc = __builtin_amdgcn_mfma_f32_16x16x32_bf16(av, bv, acc, 0, 0, 0);
  }
  int col = nt * 16 + rc;
  float bb = b1[col], alpha = al[0];
  int m0 = mt * 16 + qd * 4;
#pragma unroll
  for (int r = 0; r < 4; ++r) {
    float v = acc[r] + bb;
    hid[(size_t)(m0 + r) * 624 + col] = (v >= 0.f) ? v : alpha * v;
  }
}

// ---- logits + log_softmax ---- grid=64, block=64
__global__ void head_k(const float* __restrict__ hid, const float* __restrict__ W2,
                       const float* __restrict__ b2, float* __restrict__ out) {
  int b = blockIdx.x, t = threadIdx.x;
  float p0 = 0.f, p1 = 0.f;
  for (int k = t; k < 624; k += 64) {
    float h = hid[(size_t)b * 624 + k];
    p0 += h * W2[k * 2];
    p1 += h * W2[k * 2 + 1];
  }
#pragma unroll
  for (int off = 32; off > 0; off >>= 1) {
    p0 += __shfl_down(p0, off);
    p1 += __shfl_down(p1, off);
  }
  if (t == 0) {
    float l0 = p0 + b2[0], l1 = p1 + b2[1];
    float m = fmaxf(l0, l1);
    float lse = m + logf(expf(l0 - m) + expf(l1 - m));
    out[b * 2] = l0 - lse;
    out[b * 2 + 1] = l1 - lse;
  }
}

extern "C" void kernel_launch(void* const* d_in, const int* in_sizes, int n_in,
                              void* d_out, int out_size, void* d_ws, size_t ws_size,
                              hipStream_t stream) {
  const float* x = (const float*)d_in[0];
  const int* ei = (const int*)d_in[1];
  const float* ea = (const float*)d_in[2];
  const int* batch = (const int*)d_in[3];
  const float* Wm1 = (const float*)d_in[4];
  const float* bm1 = (const float*)d_in[5];
  const float* We1 = (const float*)d_in[6];
  const float* be1 = (const float*)d_in[7];
  const float* Ws1 = (const float*)d_in[8];
  const float* bs1 = (const float*)d_in[9];
  const float* g1 = (const float*)d_in[10];
  const float* bta1 = (const float*)d_in[11];
  const float* Wm2 = (const float*)d_in[12];
  const float* bm2 = (const float*)d_in[13];
  const float* We2 = (const float*)d_in[14];
  const float* be2 = (const float*)d_in[15];
  const float* g2 = (const float*)d_in[16];
  const float* bta2 = (const float*)d_in[17];
  const float* Wl1 = (const float*)d_in[18];
  const float* bl1 = (const float*)d_in[19];
  const float* alpha = (const float*)d_in[20];
  const float* Wl2 = (const float*)d_in[21];
  const float* bl2 = (const float*)d_in[22];
  float* out = (float*)d_out;

  const int N = in_sizes[3];      // 50000
  const int E = in_sizes[2] / 4;  // 800000
  const int nb = (N + 255) / 256; // 196 (<=256)
  const float Ninv = 1.f / (float)N;
  const int NBK = (E + 32767) >> 15;  // 25 buckets

  float* ws = (float*)d_ws;
  size_t o = 0;
  u16* acc1c = (u16*)(ws + o); o += (size_t)N * 16;  // N*32 u16
  u16* h2bf = (u16*)(ws + o);  o += (size_t)N * 104; // N*208 u16
  u16* h1bf = (u16*)(ws + o);  o += (size_t)N * 96;  // N*192 u16
  u16* xbf = (u16*)(ws + o);   o += (size_t)N * 8;   // N*16 u16
  u16* Wp1 = (u16*)(ws + o);   o += 6144;
  u16* Wp2 = (u16*)(ws + o);   o += 23296;
  u16* Wp3 = (u16*)(ws + o);   o += 389376;
  u16* Apool = (u16*)(ws + o); o += 39936;
  float* hid = ws + o;    o += 64 * 624;
  // ---- zeroed region (one memset): deg | gcnt | bns1p | bns2p ----
  int* deg = (int*)(ws + o);    o += N;
  int* gcnt = (int*)(ws + o);   o += 32;
  float* bns1p = ws + o;  o += 64 * 384;
  float* bns2p = ws + o;  o += 64 * 832;
  size_t zbytes = ((size_t)N + 32 + 64 * 384 + 64 * 832) * sizeof(float);
  // ---- end zeroed region ----
  float* aff1 = ws + o;   o += 384;
  float* aff = ws + o;    o += 832;
  float* psp = ws + o;    o += (size_t)64 * 16 * 416;
  float* pmp = ws + o;    o += (size_t)64 * 16 * 416;
  int* gstart = (int*)(ws + o); o += 64;
  int* gend = (int*)(ws + o);   o += 64;
  int* rowptr = (int*)(ws + o); o += N + 1;
  int* ord = (int*)(ws + o);    o += E;
  int* bsum = (int*)(ws + o);   o += 256;
  o = (o + 3) & ~(size_t)3;  // 16B align
  int4* se16 = (int4*)(ws + o); o += (size_t)4 * E;
  int4* bkt = (int4*)(ws + o);  o += (size_t)4 * ((size_t)NBK << 15);

  const int gconv = (N + 15) / 16;  // 3125
  const int ge = (E + 255) / 256;   // 3125
  hipMemsetAsync(deg, 0, zbytes, stream);
  prep_k<<<ge, 256, 0, stream>>>(Wm1, We1, Ws1, Wm2, Wl1, x, batch, ei, Wp1, Wp2, Wp3, xbf,
                                 gstart, gend, deg, ord, N, E);
  scanA_k<<<nb, 256, 0, stream>>>(deg, bsum, N);
  scanC_k<<<nb, 256, 0, stream>>>(deg, bsum, rowptr, N, nb);
  bucket_k<<<ge, 256, 0, stream>>>(ei, ea, ord, rowptr, gcnt, bkt, E);
  order_k<<<ge, 256, 0, stream>>>(bkt, se16, E);
  conv1_k<<<gconv, 256, 0, stream>>>(se16, rowptr, xbf, Wp1, bm1, be1, bs1, acc1c, h1bf,
                                     bns1p, N);
  bnfin1_k<<<1, 256, 0, stream>>>(bns1p, g1, bta1, Ninv, aff1);
  conv2_k<<<gconv, 256, 0, stream>>>(se16, rowptr, acc1c, h1bf, xbf, Wp1, Wp2, bm1, be1,
                                     bs1, aff1, We2, bm2, be2, bns2p, h2bf, N);
  bnfin2_k<<<2, 256, 0, stream>>>(bns2p, aff1, g2, bta2, Ninv, aff);
  pool_k<<<dim3(64, 16), 256, 0, stream>>>(h2bf, h1bf, xbf, aff, gstart, gend, psp, pmp);
  pooledprep_k<<<64, 256, 0, stream>>>(psp, pmp, gstart, gend, Apool);
  mlpgemm_k<<<dim3(4, 39), 64, 0, stream>>>(Apool, Wp3, bl1, alpha, hid);
  head_k<<<64, 64, 0, stream>>>(hid, Wl2, bl2, out);
}

// Round 16
// 309.897 us; speedup vs baseline: 1.1007x; 1.1007x over previous
//
#include <hip/hip_runtime.h>

typedef __attribute__((ext_vector_type(8))) short short8;
typedef __attribute__((ext_vector_type(4))) float f32x4;
typedef unsigned short u16;
typedef unsigned int u32;

__device__ __forceinline__ u16 f2bf(float f) {
  u32 u = __float_as_uint(f);
  u = (u + 0x7fffu + ((u >> 16) & 1u)) >> 16;
  return (u16)u;
}
__device__ __forceinline__ float bf2f(u16 v) { return __uint_as_float((u32)v << 16); }
__device__ __forceinline__ void atomAddF(float* p, float v) { unsafeAtomicAdd(p, v); }
__device__ __forceinline__ void addp(float* v, u32 p) {
  v[0] += bf2f((u16)p);
  v[1] += bf2f((u16)(p >> 16));
}

// ---- prep: pack bf16 weights + x->bf16 + graph bounds + fused deg-count/ord ----
// deg pre-zeroed by hipMemsetAsync.
__global__ void prep_k(const float* __restrict__ Wm1, const float* __restrict__ We1,
                       const float* __restrict__ Ws1, const float* __restrict__ Wm2,
                       const float* __restrict__ Wl1, const float* __restrict__ x,
                       const int* __restrict__ batch, const int* __restrict__ ei,
                       u16* __restrict__ Wp1, u16* __restrict__ Wp2, u16* __restrict__ Wp3,
                       u16* __restrict__ xbf, int* __restrict__ gstart,
                       int* __restrict__ gend, int* __restrict__ deg,
                       int* __restrict__ ord, float* __restrict__ bns1p,
                       float* __restrict__ bns2p, int N, int E) {
  int tid = blockIdx.x * 256 + threadIdx.x;
  if (tid < 64 * 192) {  // Wcat1 = [Wm1(16); We1(4); Ws1(16)], pad K to 64
    int k = tid / 192, n = tid % 192;
    float v = 0.f;
    if (k < 16) v = Wm1[k * 192 + n];
    else if (k < 20) v = We1[(k - 16) * 192 + n];
    else if (k < 36) v = Ws1[(k - 20) * 192 + n];
    Wp1[((k >> 3) * 192 + n) * 8 + (k & 7)] = f2bf(v);
  }
  if (tid < 224 * 208) {  // W_msg2, pad K 208->224
    int k = tid / 208, n = tid % 208;
    float v = (k < 208) ? Wm2[k * 208 + n] : 0.f;
    Wp2[((k >> 3) * 208 + n) * 8 + (k & 7)] = f2bf(v);
  }
  if (tid < N * 8) {  // x -> bf16, 2 elems/thread
    float2 p = *(const float2*)(x + (size_t)tid * 2);
    *(u32*)(xbf + (size_t)tid * 2) = (u32)f2bf(p.x) | ((u32)f2bf(p.y) << 16);
  }
  if (tid < N) {
    int b = batch[tid];
    if (tid == 0 || batch[tid - 1] != b) gstart[b] = tid;
    if (tid == N - 1 || batch[tid + 1] != b) gend[b] = tid;
  }
  if (tid < 64 * 384) bns1p[tid] = 0.f;
  if (tid < 64 * 832) bns2p[tid] = 0.f;
  if (tid < 1248 * 624) {
    int k = tid / 624, n = tid % 624;
    Wp3[((size_t)(k >> 3) * 624 + n) * 8 + (k & 7)] = f2bf(Wl1[(size_t)k * 624 + n]);
  }
  if (tid < E) ord[tid] = atomicAdd(&deg[ei[E + tid]], 1);  // fused count + ordinal
}

__global__ void scanA_k(const int* __restrict__ deg, int* __restrict__ bsum, int N) {
  __shared__ int sh[256];
  int t = threadIdx.x;
  int i = blockIdx.x * 256 + t;
  sh[t] = (i < N) ? deg[i] : 0;
  __syncthreads();
  for (int off = 128; off > 0; off >>= 1) {
    if (t < off) sh[t] += sh[t + off];
    __syncthreads();
  }
  if (t == 0) bsum[blockIdx.x] = sh[0];
}

__global__ void scanC_k(const int* __restrict__ deg, const int* __restrict__ bsum,
                        int* __restrict__ rowptr, int N, int nb) {
  __shared__ int sb2[256];
  __shared__ int sh[256];
  int t = threadIdx.x;
  int bv = (t < nb) ? bsum[t] : 0;
  sb2[t] = bv;
  __syncthreads();
  for (int off = 1; off < 256; off <<= 1) {
    int u = (t >= off) ? sb2[t - off] : 0;
    __syncthreads();
    sb2[t] += u;
    __syncthreads();
  }
  int bpref = (blockIdx.x == 0) ? 0 : sb2[blockIdx.x - 1];
  int i = blockIdx.x * 256 + t;
  int d = (i < N) ? deg[i] : 0;
  sh[t] = d;
  __syncthreads();
  for (int off = 1; off < 256; off <<= 1) {
    int u = (t >= off) ? sh[t - off] : 0;
    __syncthreads();
    sh[t] += u;
    __syncthreads();
  }
  int excl = sh[t] - d + bpref;
  if (i < N) {
    rowptr[i] = excl;
    if (i == N - 1) rowptr[N] = excl + d;
  }
}

// ---- scatter (no atomics): se16[rowptr[d]+ord[e]] = {src, ea01, ea23, 0} ----
__global__ void scatter_k(const int* __restrict__ ei, const float* __restrict__ ea,
                          const int* __restrict__ ord, const int* __restrict__ rowptr,
                          int4* __restrict__ se16, int E) {
  int e = blockIdx.x * 256 + threadIdx.x;
  if (e >= E) return;
  int s = ei[e], d = ei[E + e];
  float4 w = *(const float4*)(ea + (size_t)e * 4);
  int slot = rowptr[d] + ord[e];
  int4 ent;
  ent.x = s;
  ent.y = (int)((u32)f2bf(w.x) | ((u32)f2bf(w.y) << 16));
  ent.z = (int)((u32)f2bf(w.z) | ((u32)f2bf(w.w) << 16));
  ent.w = 0;
  se16[slot] = ent;
}

// ---- CONV1: gather1 (16 lanes/node) + U1(LDS) + gemm1 MFMA + h1bf + bn1 stats ----
// grid ceil(N/16), block 256 (4 waves)
__global__ void __launch_bounds__(256) conv1_k(
    const int4* __restrict__ se16, const int* __restrict__ rowptr,
    const u16* __restrict__ xbf, const u16* __restrict__ Bp,
    const float* __restrict__ bm1, const float* __restrict__ be1,
    const float* __restrict__ bs1, u16* __restrict__ acc1c, u16* __restrict__ h1bf,
    float* __restrict__ bns1p, int N) {
  __shared__ __align__(16) u16 Uls[16][72];
  __shared__ float degls[16];
  int tid = threadIdx.x;
  int nl = tid >> 4, q = tid & 15;
  int n = blockIdx.x * 16 + nl;
  bool nval = n < N;
  int j0 = nval ? rowptr[n] : 0;
  int j1 = nval ? rowptr[n + 1] : 0;
  float v[20];
#pragma unroll
  for (int i = 0; i < 20; ++i) v[i] = 0.f;
  for (int j = j0 + q; j < j1; j += 16) {
    int4 p = se16[j];
    const uint4* xs = (const uint4*)(xbf + (size_t)p.x * 16);
    uint4 x0 = xs[0], x1 = xs[1];
    addp(v + 0, x0.x); addp(v + 2, x0.y); addp(v + 4, x0.z); addp(v + 6, x0.w);
    addp(v + 8, x1.x); addp(v + 10, x1.y); addp(v + 12, x1.z); addp(v + 14, x1.w);
    addp(v + 16, (u32)p.y); addp(v + 18, (u32)p.z);
  }
#pragma unroll
  for (int i = 0; i < 20; ++i) {
    v[i] += __shfl_xor(v[i], 1);
    v[i] += __shfl_xor(v[i], 2);
    v[i] += __shfl_xor(v[i], 4);
    v[i] += __shfl_xor(v[i], 8);
  }
  float degf = (float)(j1 - j0);
  const u16* xr = xbf + (size_t)n * 16;
  {  // U1 row -> LDS: [sums20, x(n)16, 0..]; lane q writes elems q*4..q*4+3
    u32 w2[2];
#pragma unroll
    for (int jj = 0; jj < 2; ++jj) {
      int t0 = q * 4 + 2 * jj, t1 = t0 + 1;
      u16 b0 = (t0 < 20) ? f2bf(v[t0]) : ((t0 < 36 && nval) ? xr[t0 - 20] : (u16)0);
      u16 b1 = (t1 < 20) ? f2bf(v[t1]) : ((t1 < 36 && nval) ? xr[t1 - 20] : (u16)0);
      w2[jj] = (u32)b0 | ((u32)b1 << 16);
    }
    *(uint2*)&Uls[nl][q * 4] = make_uint2(w2[0], w2[1]);
  }
  if (nval) {  // acc1c row: [sx16, sea4, deg, 0..]; lane q -> elems 2q,2q+1
    int t0 = q * 2, t1 = t0 + 1;
    float f0 = (t0 < 20) ? v[t0] : ((t0 == 20) ? degf : 0.f);
    float f1 = (t1 < 20) ? v[t1] : ((t1 == 20) ? degf : 0.f);
    *(u32*)(acc1c + (size_t)n * 32 + q * 2) = (u32)f2bf(f0) | ((u32)f2bf(f1) << 16);
  }
  if (q == 0) degls[nl] = degf;
  __syncthreads();
  // Phase B: 12 n-tile jobs over 4 waves
  int w = tid >> 6, lane = tid & 63, rc = lane & 15, qd = lane >> 4;
  int slice = (blockIdx.x & 63) * 384;
  for (int nt = w; nt < 12; nt += 4) {
    f32x4 acc = {0.f, 0.f, 0.f, 0.f};
#pragma unroll
    for (int kb = 0; kb < 2; ++kb) {
      short8 av = *(const short8*)&Uls[rc][kb * 32 + qd * 8];
      short8 bv = *(const short8*)(Bp + (size_t)((kb * 4 + qd) * 192 + nt * 16 + rc) * 8);
      acc = __builtin_amdgcn_mfma_f32_16x16x32_bf16(av, bv, acc, 0, 0, 0);
    }
    int col = nt * 16 + rc;
    float bb = bm1[col] + be1[col], bsv = bs1[col];
    float ps = 0.f, pq = 0.f;
#pragma unroll
    for (int r = 0; r < 4; ++r) {
      int ml = qd * 4 + r;
      int m = blockIdx.x * 16 + ml;
      float val = acc[r] + degls[ml] * bb + bsv;
      if (m < N) {
        h1bf[(size_t)m * 192 + col] = f2bf(val);
        ps += val;
        pq += val * val;
      }
    }
    ps += __shfl_xor(ps, 16); ps += __shfl_xor(ps, 32);
    pq += __shfl_xor(pq, 16); pq += __shfl_xor(pq, 32);
    if (qd == 0) {
      atomAddF(&bns1p[slice + col], ps);
      atomAddF(&bns1p[slice + 192 + col], pq);
    }
  }
}

// ---- bn1 finalize ---- 1 block, 256 threads
__global__ void bnfin1_k(const float* __restrict__ bns1p, const float* __restrict__ g1,
                         const float* __restrict__ bta1, float Ninv,
                         float* __restrict__ aff1) {
  int c = threadIdx.x;
  if (c >= 192) return;
  float sm = 0.f, sq = 0.f;
  for (int k = 0; k < 64; ++k) {
    sm += bns1p[k * 384 + c];
    sq += bns1p[k * 384 + 192 + c];
  }
  float m1 = sm * Ninv;
  float var = sq * Ninv - m1 * m1;
  float s1 = g1[c] * rsqrtf(var + 1e-5f);
  aff1[c] = s1;
  aff1[192 + c] = bta1[c] - m1 * s1;
}

// ---- CONV2: gather2 (16 lanes/node) + U2(LDS) + gemmq2 (V in LDS) + gemm2 + bn2 ----
// grid ceil(N/16), block 256 (4 waves)
__global__ void __launch_bounds__(256) conv2_k(
    const int4* __restrict__ se16, const int* __restrict__ rowptr,
    const u16* __restrict__ acc1c, const u16* __restrict__ h1bf,
    const u16* __restrict__ xbf, const u16* __restrict__ Bp1, const u16* __restrict__ Bp2,
    const float* __restrict__ bm1, const float* __restrict__ be1,
    const float* __restrict__ bs1, const float* __restrict__ aff1,
    const float* __restrict__ We2, const float* __restrict__ bm2,
    const float* __restrict__ be2, float* __restrict__ bns2p,
    u16* __restrict__ h2bf, int N) {
  __shared__ __align__(16) u16 Uls[16][72];
  __shared__ __align__(16) u16 Vls[16][232];
  __shared__ float degls[16], sdegls[16], eals[16][4];
  int tid = threadIdx.x;
  int nl = tid >> 4, q = tid & 15;
  int n = blockIdx.x * 16 + nl;
  bool nval = n < N;
  int j0 = nval ? rowptr[n] : 0;
  int j1 = nval ? rowptr[n + 1] : 0;
  float v[21];
#pragma unroll
  for (int i = 0; i < 21; ++i) v[i] = 0.f;
  for (int j = j0 + q; j < j1; j += 16) {
    int s = se16[j].x;
    const uint4* cr = (const uint4*)(acc1c + (size_t)s * 32);
    uint4 c0 = cr[0], c1 = cr[1], c2 = cr[2];
    addp(v + 0, c0.x); addp(v + 2, c0.y); addp(v + 4, c0.z); addp(v + 6, c0.w);
    addp(v + 8, c1.x); addp(v + 10, c1.y); addp(v + 12, c1.z); addp(v + 14, c1.w);
    addp(v + 16, c2.x); addp(v + 18, c2.y);
    v[20] += bf2f((u16)c2.z);
  }
#pragma unroll
  for (int i = 0; i < 21; ++i) {
    v[i] += __shfl_xor(v[i], 1);
    v[i] += __shfl_xor(v[i], 2);
    v[i] += __shfl_xor(v[i], 4);
    v[i] += __shfl_xor(v[i], 8);
  }
  const u16* selfr = acc1c + (size_t)n * 32;
  {  // U2 row -> LDS: [sums20, self sx16, 0..]; lane q writes elems q*4..q*4+3
    u32 w2[2];
#pragma unroll
    for (int jj = 0; jj < 2; ++jj) {
      int t0 = q * 4 + 2 * jj, t1 = t0 + 1;
      u16 b0 = (t0 < 20) ? f2bf(v[t0]) : ((t0 < 36 && nval) ? selfr[t0 - 20] : (u16)0);
      u16 b1 = (t1 < 20) ? f2bf(v[t1]) : ((t1 < 36 && nval) ? selfr[t1 - 20] : (u16)0);
      w2[jj] = (u32)b0 | ((u32)b1 << 16);
    }
    *(uint2*)&Uls[nl][q * 4] = make_uint2(w2[0], w2[1]);
  }
  {  // V tail cols [192..224): self sx16 then zeros; lane q -> elems 192+2q, +1
    int t0 = q * 2, t1 = t0 + 1;
    u16 b0 = (t0 < 16 && nval) ? selfr[t0] : (u16)0;
    u16 b1 = (t1 < 16 && nval) ? selfr[t1] : (u16)0;
    *(u32*)&Vls[nl][192 + q * 2] = (u32)b0 | ((u32)b1 << 16);
  }
  if (q == 0) sdegls[nl] = v[20];
  if (q == 1) degls[nl] = nval ? bf2f(selfr[20]) : 0.f;
  if (q == 2) {
#pragma unroll
    for (int k = 0; k < 4; ++k) eals[nl][k] = nval ? bf2f(selfr[16 + k]) : 0.f;
  }
  __syncthreads();
  // Phase B: gemmq2 -> Vls[:,0..192), 12 jobs / 4 waves
  int w = tid >> 6, lane = tid & 63, rc = lane & 15, qd = lane >> 4;
  for (int nt = w; nt < 12; nt += 4) {
    f32x4 acc = {0.f, 0.f, 0.f, 0.f};
#pragma unroll
    for (int kb = 0; kb < 2; ++kb) {
      short8 av = *(const short8*)&Uls[rc][kb * 32 + qd * 8];
      short8 bv = *(const short8*)(Bp1 + (size_t)((kb * 4 + qd) * 192 + nt * 16 + rc) * 8);
      acc = __builtin_amdgcn_mfma_f32_16x16x32_bf16(av, bv, acc, 0, 0, 0);
    }
    int col = nt * 16 + rc;
    float s1 = aff1[col], t1 = aff1[192 + col];
    float bb = bm1[col] + be1[col], bsv = bs1[col];
#pragma unroll
    for (int r = 0; r < 4; ++r) {
      int ml = qd * 4 + r;
      float qv = acc[r] + sdegls[ml] * bb + degls[ml] * bsv;
      Vls[ml][col] = f2bf(qv * s1 + degls[ml] * t1);
    }
  }
  __syncthreads();
  // Phase C: gemm2, A = Vls, 13 jobs / 4 waves
  int slice = (blockIdx.x & 63) * 832;
  for (int nt = w; nt < 13; nt += 4) {
    f32x4 acc = {0.f, 0.f, 0.f, 0.f};
#pragma unroll
    for (int kb = 0; kb < 7; ++kb) {
      short8 av = *(const short8*)&Vls[rc][kb * 32 + qd * 8];
      short8 bv = *(const short8*)(Bp2 + (size_t)((kb * 4 + qd) * 208 + nt * 16 + rc) * 8);
      acc = __builtin_amdgcn_mfma_f32_16x16x32_bf16(av, bv, acc, 0, 0, 0);
    }
    int col = nt * 16 + rc;
    float w0 = We2[col], w1 = We2[208 + col], w2 = We2[416 + col], w3 = We2[624 + col];
    float bb2 = bm2[col] + be2[col];
    bool c192 = col < 192;
    float s1 = c192 ? aff1[col] : 0.f;
    float t1 = c192 ? aff1[192 + col] : 0.f;
    float ps = 0.f, pq = 0.f;
#pragma unroll
    for (int r = 0; r < 4; ++r) {
      int ml = qd * 4 + r;
      int m = blockIdx.x * 16 + ml;
      bool mv = m < N;
      float x1 = 0.f;
      if (mv) {
        x1 = c192 ? (bf2f(h1bf[(size_t)m * 192 + col]) * s1 + t1)
                  : bf2f(xbf[(size_t)m * 16 + (col - 192)]);
      }
      float val = acc[r] + eals[ml][0] * w0 + eals[ml][1] * w1 + eals[ml][2] * w2 +
                  eals[ml][3] * w3 + degls[ml] * bb2 + x1;
      if (mv) {
        h2bf[(size_t)m * 208 + col] = f2bf(val);
        ps += val;
        pq += val * val;
      }
    }
    ps += __shfl_xor(ps, 16); ps += __shfl_xor(ps, 32);
    pq += __shfl_xor(pq, 16); pq += __shfl_xor(pq, 32);
    if (qd == 0) {
      atomAddF(&bns2p[slice + col], ps);
      atomAddF(&bns2p[slice + 416 + col], pq);
    }
  }
}

// ---- bn finalize: unified affine table ---- grid 2x256
__global__ void bnfin2_k(const float* __restrict__ bns2p, const float* __restrict__ aff1,
                         const float* __restrict__ g2, const float* __restrict__ bta2,
                         float Ninv, float* __restrict__ aff) {
  int f = blockIdx.x * 256 + threadIdx.x;
  if (f >= 416) return;
  float sc, sh;
  if (f < 208) {
    float sm = 0.f, sq = 0.f;
    for (int k = 0; k < 64; ++k) {
      sm += bns2p[k * 832 + f];
      sq += bns2p[k * 832 + 416 + f];
    }
    float m2 = sm * Ninv;
    float var = sq * Ninv - m2 * m2;
    sc = g2[f] * rsqrtf(var + 1e-5f);
    sh = bta2[f] - m2 * sc;
  } else if (f < 400) {
    sc = aff1[f - 208];
    sh = aff1[192 + (f - 208)];
  } else {
    sc = 1.f;
    sh = 0.f;
  }
  aff[f] = sc;
  aff[416 + f] = sh;
}

// ---- pooling: feature-pair threads, partial stores ---- grid=(64,16), block=256
__global__ void pool_k(const u16* __restrict__ h2bf, const u16* __restrict__ h1bf,
                       const u16* __restrict__ xbf, const float* __restrict__ aff,
                       const int* __restrict__ gstart, const int* __restrict__ gend,
                       float* __restrict__ psp, float* __restrict__ pmp) {
  int b = blockIdx.x, sub = blockIdx.y;
  int t = threadIdx.x;
  if (t >= 208) return;
  int s0 = gstart[b], e0 = gend[b];
  int cnt = (s0 <= e0) ? e0 - s0 + 1 : 0;
  int per = (cnt + 15) >> 4;
  int n0 = s0 + sub * per;
  int n1 = min(n0 + per, s0 + cnt);
  int f = 2 * t;
  const u16* src;
  int stride;
  if (f < 208) { src = h2bf + f; stride = 208; }
  else if (f < 400) { src = h1bf + (f - 208); stride = 192; }
  else { src = xbf + (f - 400); stride = 16; }
  float sc0 = aff[f], sc1 = aff[f + 1];
  float sh0 = aff[416 + f], sh1 = aff[417 + f];
  float s0f = 0.f, s1f = 0.f, m0f = -3.4e38f, m1f = -3.4e38f;
  for (int n = n0; n < n1; ++n) {
    u32 p = *(const u32*)(src + (size_t)n * stride);
    float v0 = bf2f((u16)p) * sc0 + sh0;
    float v1 = bf2f((u16)(p >> 16)) * sc1 + sh1;
    s0f += v0; s1f += v1;
    m0f = fmaxf(m0f, v0); m1f = fmaxf(m1f, v1);
  }
  size_t idx = ((size_t)(b * 16 + sub)) * 416 + f;
  *(float2*)(psp + idx) = make_float2(s0f, s1f);
  *(float2*)(pmp + idx) = make_float2(m0f, m1f);
}

// ---- pooled partial reduce -> bf16 A matrix [64 x 1248] ---- grid=64, block=256
__global__ void pooledprep_k(const float* __restrict__ psp, const float* __restrict__ pmp,
                             const int* __restrict__ gstart, const int* __restrict__ gend,
                             u16* __restrict__ Apool) {
  int b = blockIdx.x, t = threadIdx.x;
  int cnt = gend[b] - gstart[b] + 1;
  float inv = 1.f / (float)max(cnt, 1);
  for (int f = t; f < 416; f += 256) {
    float s = 0.f, m = -3.4e38f;
    for (int k = 0; k < 16; ++k) {
      size_t idx = ((size_t)(b * 16 + k)) * 416 + f;
      s += psp[idx];
      m = fmaxf(m, pmp[idx]);
    }
    u16* row = Apool + (size_t)b * 1248;
    row[f] = f2bf(s);
    row[416 + f] = f2bf((cnt > 0) ? m : 0.f);
    row[832 + f] = f2bf(s * inv);
  }
}

// ---- MLP layer 1 via MFMA ---- grid=(4,39), block=64
__global__ void mlpgemm_k(const u16* __restrict__ A, const u16* __restrict__ Bp,
                          const float* __restrict__ b1, const float* __restrict__ al,
                          float* __restrict__ hid) {
  int lane = threadIdx.x;
  int mt = blockIdx.x, nt = blockIdx.y;
  int rc = lane & 15, qd = lane >> 4;
  f32x4 acc = {0.f, 0.f, 0.f, 0.f};
  const u16* Ap = A + (size_t)(mt * 16 + rc) * 1248 + qd * 8;
  const u16* Bq = Bp + (size_t)(qd * 624 + nt * 16 + rc) * 8;
  for (int kb = 0; kb < 39; ++kb) {
    short8 av = *(const short8*)(Ap + kb * 32);
    short8 bv = *(const short8*)(Bq + (size_t)kb * 4 * 624 * 8);
    acc = __builtin_amdgcn_mfma_f32_16x16x32_bf16(av, bv, acc, 0, 0, 0);
  }
  int col = nt * 16 + rc;
  float bb = b1[col], alpha = al[0];
  int m0 = mt * 16 + qd * 4;
#pragma unroll
  for (int r = 0; r < 4; ++r) {
    float v = acc[r] + bb;
    hid[(size_t)(m0 + r) * 624 + col] = (v >= 0.f) ? v : alpha * v;
  }
}

// ---- logits + log_softmax ---- grid=64, block=64
__global__ void head_k(const float* __restrict__ hid, const float* __restrict__ W2,
                       const float* __restrict__ b2, float* __restrict__ out) {
  int b = blockIdx.x, t = threadIdx.x;
  float p0 = 0.f, p1 = 0.f;
  for (int k = t; k < 624; k += 64) {
    float h = hid[(size_t)b * 624 + k];
    p0 += h * W2[k * 2];
    p1 += h * W2[k * 2 + 1];
  }
#pragma unroll
  for (int off = 32; off > 0; off >>= 1) {
    p0 += __shfl_down(p0, off);
    p1 += __shfl_down(p1, off);
  }
  if (t == 0) {
    float l0 = p0 + b2[0], l1 = p1 + b2[1];
    float m = fmaxf(l0, l1);
    float lse = m + logf(expf(l0 - m) + expf(l1 - m));
    out[b * 2] = l0 - lse;
    out[b * 2 + 1] = l1 - lse;
  }
}

extern "C" void kernel_launch(void* const* d_in, const int* in_sizes, int n_in,
                              void* d_out, int out_size, void* d_ws, size_t ws_size,
                              hipStream_t stream) {
  const float* x = (const float*)d_in[0];
  const int* ei = (const int*)d_in[1];
  const float* ea = (const float*)d_in[2];
  const int* batch = (const int*)d_in[3];
  const float* Wm1 = (const float*)d_in[4];
  const float* bm1 = (const float*)d_in[5];
  const float* We1 = (const float*)d_in[6];
  const float* be1 = (const float*)d_in[7];
  const float* Ws1 = (const float*)d_in[8];
  const float* bs1 = (const float*)d_in[9];
  const float* g1 = (const float*)d_in[10];
  const float* bta1 = (const float*)d_in[11];
  const float* Wm2 = (const float*)d_in[12];
  const float* bm2 = (const float*)d_in[13];
  const float* We2 = (const float*)d_in[14];
  const float* be2 = (const float*)d_in[15];
  const float* g2 = (const float*)d_in[16];
  const float* bta2 = (const float*)d_in[17];
  const float* Wl1 = (const float*)d_in[18];
  const float* bl1 = (const float*)d_in[19];
  const float* alpha = (const float*)d_in[20];
  const float* Wl2 = (const float*)d_in[21];
  const float* bl2 = (const float*)d_in[22];
  float* out = (float*)d_out;

  const int N = in_sizes[3];      // 50000
  const int E = in_sizes[2] / 4;  // 800000
  const int nb = (N + 255) / 256; // 196 (<=256)
  const float Ninv = 1.f / (float)N;

  float* ws = (float*)d_ws;
  size_t o = 0;
  u16* acc1c = (u16*)(ws + o); o += (size_t)N * 16;  // N*32 u16
  u16* h2bf = (u16*)(ws + o);  o += (size_t)N * 104; // N*208 u16
  u16* h1bf = (u16*)(ws + o);  o += (size_t)N * 96;  // N*192 u16
  u16* xbf = (u16*)(ws + o);   o += (size_t)N * 8;   // N*16 u16
  u16* Wp1 = (u16*)(ws + o);   o += 6144;
  u16* Wp2 = (u16*)(ws + o);   o += 23296;
  u16* Wp3 = (u16*)(ws + o);   o += 389376;
  u16* Apool = (u16*)(ws + o); o += 39936;
  float* hid = ws + o;    o += 64 * 624;
  float* bns1p = ws + o;  o += 64 * 384;
  float* bns2p = ws + o;  o += 64 * 832;
  float* aff1 = ws + o;   o += 384;
  float* aff = ws + o;    o += 832;
  float* psp = ws + o;    o += (size_t)64 * 16 * 416;
  float* pmp = ws + o;    o += (size_t)64 * 16 * 416;
  int* gstart = (int*)(ws + o); o += 64;
  int* gend = (int*)(ws + o);   o += 64;
  int* deg = (int*)(ws + o);    o += N;
  int* rowptr = (int*)(ws + o); o += N + 1;
  int* ord = (int*)(ws + o);    o += E;
  int* bsum = (int*)(ws + o);   o += 256;
  o = (o + 3) & ~(size_t)3;  // 16B align for int4
  int4* se16 = (int4*)(ws + o); o += (size_t)4 * E;

  const int gconv = (N + 15) / 16;  // 3125
  const int ge = (E + 255) / 256;   // 3125
  hipMemsetAsync(deg, 0, (size_t)N * sizeof(int), stream);
  prep_k<<<ge, 256, 0, stream>>>(Wm1, We1, Ws1, Wm2, Wl1, x, batch, ei, Wp1, Wp2, Wp3, xbf,
                                 gstart, gend, deg, ord, bns1p, bns2p, N, E);
  scanA_k<<<nb, 256, 0, stream>>>(deg, bsum, N);
  scanC_k<<<nb, 256, 0, stream>>>(deg, bsum, rowptr, N, nb);
  scatter_k<<<ge, 256, 0, stream>>>(ei, ea, ord, rowptr, se16, E);
  conv1_k<<<gconv, 256, 0, stream>>>(se16, rowptr, xbf, Wp1, bm1, be1, bs1, acc1c, h1bf,
                                     bns1p, N);
  bnfin1_k<<<1, 256, 0, stream>>>(bns1p, g1, bta1, Ninv, aff1);
  conv2_k<<<gconv, 256, 0, stream>>>(se16, rowptr, acc1c, h1bf, xbf, Wp1, Wp2, bm1, be1,
                                     bs1, aff1, We2, bm2, be2, bns2p, h2bf, N);
  bnfin2_k<<<2, 256, 0, stream>>>(bns2p, aff1, g2, bta2, Ninv, aff);
  pool_k<<<dim3(64, 16), 256, 0, stream>>>(h2bf, h1bf, xbf, aff, gstart, gend, psp, pmp);
  pooledprep_k<<<64, 256, 0, stream>>>(psp, pmp, gstart, gend, Apool);
  mlpgemm_k<<<dim3(4, 39), 64, 0, stream>>>(Apool, Wp3, bl1, alpha, hid);
  head_k<<<64, 64, 0, stream>>>(hid, Wl2, bl2, out);
}